// Round 10
// baseline (892.704 us; speedup 1.0000x reference)
//
#include <hip/hip_runtime.h>
#include <hip/hip_bf16.h>

#define N_NODES 50000
#define N_EDGES 1600000
#define N_GRAPHS 256
#define NEG_SLOPE 0.2f
#define BN_EPS 1e-5f

typedef __hip_bfloat16 bf16;
typedef __attribute__((ext_vector_type(8))) short s16x8;   // 8 bf16 in 4 VGPRs
typedef __attribute__((ext_vector_type(4))) float f32x4;
typedef __attribute__((ext_vector_type(2))) unsigned u32x2;

__device__ __forceinline__ float b2f(bf16 v){ return __bfloat162float(v); }
__device__ __forceinline__ bf16 f2b(float v){ return __float2bfloat16(v); }
__device__ __forceinline__ float us2f(unsigned short u){ return __uint_as_float(((unsigned)u)<<16); }
__device__ __forceinline__ unsigned short f2us(float v){ bf16 b = f2b(v); return *(unsigned short*)&b; }
__device__ __forceinline__ unsigned pk2(float a, float b){ return (unsigned)f2us(a) | ((unsigned)f2us(b)<<16); }
__device__ __forceinline__ float ldF(const void* p, size_t i, int m){
  return m ? ((const float*)p)[i] : b2f(((const bf16*)p)[i]);
}
__device__ __forceinline__ float sane(float v){
  return (v == v && fabsf(v) < 1e30f) ? v : 0.f;
}
__device__ __forceinline__ float sel4(const float v[4], int h){
  float r = v[0];
  r = (h==1) ? v[1] : r;
  r = (h==2) ? v[2] : r;
  r = (h==3) ? v[3] : r;
  return r;
}
// acc[0..7] += w * (8 bf16 packed in uint4)
__device__ __forceinline__ void acc8(float* acc, float w, uint4 u){
  acc[0] += w*us2f((unsigned short)(u.x & 0xffff)); acc[1] += w*us2f((unsigned short)(u.x >> 16));
  acc[2] += w*us2f((unsigned short)(u.y & 0xffff)); acc[3] += w*us2f((unsigned short)(u.y >> 16));
  acc[4] += w*us2f((unsigned short)(u.z & 0xffff)); acc[5] += w*us2f((unsigned short)(u.z >> 16));
  acc[6] += w*us2f((unsigned short)(u.w & 0xffff)); acc[7] += w*us2f((unsigned short)(u.w >> 16));
}
__device__ __forceinline__ void unp8(float* o, uint4 u){
  o[0] = us2f((unsigned short)(u.x & 0xffff)); o[1] = us2f((unsigned short)(u.x >> 16));
  o[2] = us2f((unsigned short)(u.y & 0xffff)); o[3] = us2f((unsigned short)(u.y >> 16));
  o[4] = us2f((unsigned short)(u.z & 0xffff)); o[5] = us2f((unsigned short)(u.z >> 16));
  o[6] = us2f((unsigned short)(u.w & 0xffff)); o[7] = us2f((unsigned short)(u.w >> 16));
}
__device__ __forceinline__ s16x8 pk8(const float* v){
  s16x8 r;
  #pragma unroll
  for(int j=0;j<8;j++) r[j] = (short)f2us(v[j]);
  return r;
}
// wave-internal LDS fence: all prior ds_writes complete + no compiler reordering
__device__ __forceinline__ void wave_lds_fence(){
  __builtin_amdgcn_sched_barrier(0);
  asm volatile("s_waitcnt lgkmcnt(0)" ::: "memory");
  __builtin_amdgcn_sched_barrier(0);
}

// block-level dtype detection
__device__ int detect_mode_block(const void* x){
  __shared__ int s_ins;
  if(threadIdx.x == 0) s_ins = 0;
  __syncthreads();
  const unsigned short* u = (const unsigned short*)x;
  int c = 0;
  for(int i = threadIdx.x; i < 1024; i += blockDim.x){
    float v = fabsf(us2f(u[i]));
    if(!(v > 1e-6f && v < 1e4f)) c++;
  }
  if(c) atomicAdd(&s_ins, c);
  __syncthreads();
  return (s_ins > 128) ? 1 : 0;   // 1 => f32
}

// ---------------- weight bank layout ----------------
#define NSEG 33
struct Bank { const void* p[NSEG]; int n[NSEG]; int off[NSEG]; };

// ---------------- mega prep kernel: count | convert | wt | we (all independent) ----------------
// count partition: 4 edges/thread (independent atomic chains -> MLP=4)
#define PREP_COUNT 1563
#define PREP_CONV  (64*NSEG)
#define PREP_WT    160
__global__ void k_prep(Bank bk, const void* xdet, const int* __restrict__ dst,
                       int* __restrict__ cnt, float* __restrict__ wbank,
                       bf16* __restrict__ wt,
                       const void* pW1, const void* pW2, const void* pWg1, const void* pWg2,
                       const void* pWe1, const void* pae1, const void* pWe2, const void* pae2,
                       float* __restrict__ w_e){
  int bid = blockIdx.x;
  int t = threadIdx.x;
  if(bid < PREP_COUNT){
    int base = bid*1024 + t;
    #pragma unroll
    for(int k=0;k<4;k++){
      int e = base + k*256;
      if(e < N_EDGES){
        int d = dst[e]; if((unsigned)d >= N_NODES) d = 0;
        atomicAdd(&cnt[d], 1);
      }
    }
    return;
  }
  int m = detect_mode_block(xdet);
  if(bid < PREP_COUNT + PREP_CONV){
    int b2 = bid - PREP_COUNT;
    int seg = b2 >> 6;
    int i = (b2 & 63)*256 + t;
    if(i < bk.n[seg]) wbank[bk.off[seg] + i] = ldF(bk.p[seg], i, m);
  } else if(bid < PREP_COUNT + PREP_CONV + PREP_WT){
    int i = (bid - PREP_COUNT - PREP_CONV)*256 + t;
    // wt layout: [0,16384) Wt1[256][64]; [16384,32768) Wt2[64][256]; then Wtg1,Wtg2 [64][64]
    if(i < 16384){
      int c = i >> 6, k = i & 63;
      wt[i] = f2b(ldF(pW1, k*256 + c, m));
    } else if(i < 32768){
      int j = i - 16384; int c = j >> 8, k = j & 255;
      wt[i] = f2b(ldF(pW2, k*64 + c, m));
    } else if(i < 36864){
      int j = i - 32768; int c = j >> 6, k = j & 63;
      wt[i] = f2b(ldF(pWg1, k*64 + c, m));
    } else if(i < 40960){
      int j = i - 36864; int c = j >> 6, k = j & 63;
      wt[i] = f2b(ldF(pWg2, k*64 + c, m));
    }
  } else {
    if(t < 32){
      int h = t >> 3, k = t & 7;
      float s = 0.f;
      for(int d=0;d<64;d++) s += ldF(pWe1, k*256 + h*64 + d, m) * ldF(pae1, h*64 + d, m);
      w_e[t] = s;
    } else if(t < 40){
      int k = t - 32;
      float s = 0.f;
      for(int d=0;d<64;d++) s += ldF(pWe2, k*64 + d, m) * ldF(pae2, d, m);
      w_e[t] = s;
    }
  }
}

// ---------------- CSR build ----------------
__global__ void k_blocksum(const int* __restrict__ cnt, int* __restrict__ bsum){
  __shared__ int s[256];
  int i = blockIdx.x*256 + threadIdx.x;
  s[threadIdx.x] = (i < N_NODES) ? cnt[i] : 0;
  __syncthreads();
  for(int o=128;o>0;o>>=1){ if(threadIdx.x<o) s[threadIdx.x]+=s[threadIdx.x+o]; __syncthreads(); }
  if(threadIdx.x==0) bsum[blockIdx.x]=s[0];
}

// scan over bsum inlined (nb <= 256), then per-block scan of cnt
__global__ void k_scan_write(const int* __restrict__ cnt, const int* __restrict__ bsum,
                             int* __restrict__ rp, float* __restrict__ dinv, int nb){
  __shared__ int sb[256];
  __shared__ int s[256];
  int t = threadIdx.x; int i = blockIdx.x*256 + t;
  sb[t] = (t<nb) ? bsum[t] : 0;
  __syncthreads();
  for(int o=1;o<256;o<<=1){ int v=(t>=o)?sb[t-o]:0; __syncthreads(); sb[t]+=v; __syncthreads(); }
  int bofs = (blockIdx.x==0) ? 0 : sb[blockIdx.x-1];
  int v = (i<N_NODES) ? cnt[i] : 0;
  s[t]=v; __syncthreads();
  for(int o=1;o<256;o<<=1){ int a=(t>=o)?s[t-o]:0; __syncthreads(); s[t]+=a; __syncthreads(); }
  if(i<N_NODES){
    rp[i+1] = s[t] + bofs;
    dinv[i] = rsqrtf((float)v + 1.f);
  }
  if(i==0) rp[0]=0;
}

// fill CSR (SoA): srcs[slot] 4B, ed4[slot] 8B (4 bf16), ed1[slot] 4B (1 bf16 in low16)
// Plain stores (NOT nontemporal): dense slots merge in L2 before writeback (round-6 lesson).
// 2 edges per thread: two independent atomic+scatter chains overlap (MLP=2).
__global__ void k_fill(const int* __restrict__ src, const int* __restrict__ dst,
                       const int* __restrict__ rp, int* __restrict__ fill,
                       const void* __restrict__ ea, const void* __restrict__ xdet,
                       const float* __restrict__ w_e,
                       int* __restrict__ srcs, u32x2* __restrict__ ed4,
                       unsigned* __restrict__ ed1){
  int m = detect_mode_block(xdet);
  int base = blockIdx.x*512 + threadIdx.x;
  #pragma unroll
  for(int k2=0;k2<2;k2++){
    int e = base + k2*256;
    if(e < N_EDGES){
      int d = dst[e]; if((unsigned)d >= N_NODES) d = 0;
      int p = atomicAdd(&fill[d], 1);
      int slot = rp[d] + p;
      if((unsigned)slot < N_EDGES){
        int sv = src[e]; if((unsigned)sv >= N_NODES) sv = 0;
        float a[8];
        if(m){
          const float* eaf = (const float*)ea;
          float4 lo = *(const float4*)&eaf[(size_t)e*8];
          float4 hi = *(const float4*)&eaf[(size_t)e*8 + 4];
          a[0]=lo.x; a[1]=lo.y; a[2]=lo.z; a[3]=lo.w;
          a[4]=hi.x; a[5]=hi.y; a[6]=hi.z; a[7]=hi.w;
        } else {
          #pragma unroll
          for(int k=0;k<8;k++) a[k] = b2f(((const bf16*)ea)[(size_t)e*8 + k]);
        }
        unsigned d4[4];
        #pragma unroll
        for(int h=0;h<4;h++){
          float s = 0.f;
          #pragma unroll
          for(int k=0;k<8;k++) s += a[k]*w_e[h*8+k];
          d4[h] = f2us(s);
        }
        float s1 = 0.f;
        #pragma unroll
        for(int k=0;k<8;k++) s1 += a[k]*w_e[32+k];
        srcs[slot] = sv;
        u32x2 e4;
        e4[0] = d4[0] | (d4[1] << 16);
        e4[1] = d4[2] | (d4[3] << 16);
        ed4[slot] = e4;
        ed1[slot] = (unsigned)f2us(s1);
      }
    }
  }
}

// ---------------- MFMA GEMM layer 1: raw x [M,64] x wt1 -> hp [M,256] bf16 + fused alpha dots ----------------
__global__ __launch_bounds__(256) void k_gemmA_mfma(
    const void* __restrict__ x,       // raw input, bf16 or f32 (mode-detected)
    const bf16* __restrict__ wt1,     // [256][64] = Wt1[col][k]
    bf16* __restrict__ hp, int M,
    const float* __restrict__ asrc,   // [256]
    const float* __restrict__ adst,   // [256]
    float* __restrict__ als4, float* __restrict__ ald4)
{
  int m = detect_mode_block(x);
  const int tid = threadIdx.x;
  const int w = tid >> 6, l = tid & 63;
  const int lr = l & 15, lg = l >> 4;
  const int bm = blockIdx.x*64 + w*16;
  const int row = min(bm + lr, M-1);
  s16x8 a0, a1;
  if(m){
    const float* ar = (const float*)x + (size_t)row*64;
    float va[8], vb[8];
    #pragma unroll
    for(int j=0;j<8;j++){ va[j] = ar[8*lg + j]; vb[j] = ar[32 + 8*lg + j]; }
    a0 = pk8(va); a1 = pk8(vb);
  } else {
    const uint4* ar = (const uint4*)((const bf16*)x + (size_t)row*64);
    uint4 a0u = ar[lg];
    uint4 a1u = ar[4 + lg];
    a0 = *(s16x8*)&a0u; a1 = *(s16x8*)&a1u;
  }
  unsigned short* out = (unsigned short*)hp;
  const int orow0 = bm + lg*4;
  float p_s[4][4] = {};   // [head][r]
  float p_d[4][4] = {};
  #pragma unroll
  for(int ct = 0; ct < 16; ct++){
    const uint4* brow = (const uint4*)(wt1 + (size_t)(ct*16 + lr)*64);
    uint4 b0u = brow[lg];
    uint4 b1u = brow[4 + lg];
    f32x4 acc = {0.f, 0.f, 0.f, 0.f};
    acc = __builtin_amdgcn_mfma_f32_16x16x32_bf16(a0, *(s16x8*)&b0u, acc, 0, 0, 0);
    acc = __builtin_amdgcn_mfma_f32_16x16x32_bf16(a1, *(s16x8*)&b1u, acc, 0, 0, 0);
    float a_s = asrc[ct*16 + lr];
    float a_d = adst[ct*16 + lr];
    int hh = ct >> 2;
    #pragma unroll
    for(int r = 0; r < 4; r++){
      p_s[hh][r] += acc[r]*a_s;
      p_d[hh][r] += acc[r]*a_d;
      int rr = orow0 + r;
      if(rr < M) out[(size_t)rr*256 + ct*16 + lr] = f2us(acc[r]);
    }
  }
  #pragma unroll
  for(int o = 1; o < 16; o <<= 1){
    #pragma unroll
    for(int hh=0; hh<4; hh++)
      #pragma unroll
      for(int r=0; r<4; r++){
        p_s[hh][r] += __shfl_xor(p_s[hh][r], o);
        p_d[hh][r] += __shfl_xor(p_d[hh][r], o);
      }
  }
  if(lr == 0){
    #pragma unroll
    for(int r=0;r<4;r++){
      int rr = orow0 + r;
      if(rr < M){
        #pragma unroll
        for(int hh=0;hh<4;hh++){
          als4[rr*4 + hh] = p_s[hh][r];
          ald4[rr*4 + hh] = p_d[hh][r];
        }
      }
    }
  }
}

// ---------------- MFMA GEMM layers 2-4 (optional fused single-head alpha dots) ----------------
template<int KIN>
__global__ __launch_bounds__(256) void k_gemmB_mfma(
    const bf16* __restrict__ A, const bf16* __restrict__ Wt,
    bf16* __restrict__ C, int M,
    const float* __restrict__ bnsums, const float* __restrict__ bng, const float* __restrict__ bnb,
    const float* __restrict__ asrc, const float* __restrict__ adst,
    float* __restrict__ als, float* __restrict__ ald)
{
  __shared__ float st_s[KIN];
  __shared__ float st_t[KIN];
  const int tid = threadIdx.x;
  if(tid < KIN){
    const float invN = 1.0f / (float)N_NODES;
    float mean = bnsums[tid]*invN;
    float var  = fmaxf(bnsums[KIN+tid]*invN - mean*mean, 0.f);
    float s = bng[tid]*rsqrtf(var + BN_EPS);
    st_s[tid] = s;
    st_t[tid] = bnb[tid] - mean*s;
  }
  __syncthreads();
  const int w = tid >> 6, l = tid & 63;
  const int lr = l & 15, lg = l >> 4;
  const int bm = blockIdx.x*64 + w*16;
  const int arow_i = bm + lr;
  const uint4* arow = (const uint4*)(A + (size_t)min(arow_i, M-1)*KIN);
  f32x4 acc[4];
  #pragma unroll
  for(int ct=0;ct<4;ct++) acc[ct] = (f32x4){0.f,0.f,0.f,0.f};
  #pragma unroll
  for(int k0 = 0; k0 < KIN; k0 += 32){
    uint4 au = arow[(k0 >> 3) + lg];          // elems k0 + 8*lg .. +7
    int c0 = k0 + lg*8;
    float v[8]; unp8(v, au);
    #pragma unroll
    for(int j = 0; j < 8; j++){
      float y = sane(v[j])*st_s[c0+j] + st_t[c0+j];
      v[j] = fmaxf(y, 0.f);
    }
    s16x8 af = pk8(v);
    #pragma unroll
    for(int ct = 0; ct < 4; ct++){
      const uint4* brow = (const uint4*)(Wt + (size_t)(ct*16 + lr)*KIN);
      uint4 bu = brow[(k0 >> 3) + lg];
      acc[ct] = __builtin_amdgcn_mfma_f32_16x16x32_bf16(af, *(s16x8*)&bu, acc[ct], 0, 0, 0);
    }
  }
  unsigned short* out = (unsigned short*)C;
  const int orow0 = bm + lg*4;
  #pragma unroll
  for(int ct = 0; ct < 4; ct++){
    #pragma unroll
    for(int r = 0; r < 4; r++){
      int rr = orow0 + r;
      if(rr < M) out[(size_t)rr*64 + ct*16 + lr] = f2us(acc[ct][r]);
    }
  }
  if(als){
    float p_s[4] = {0.f,0.f,0.f,0.f};
    float p_d[4] = {0.f,0.f,0.f,0.f};
    #pragma unroll
    for(int ct=0;ct<4;ct++){
      float a_s = asrc[ct*16 + lr];
      float a_d = adst[ct*16 + lr];
      #pragma unroll
      for(int r=0;r<4;r++){
        p_s[r] += acc[ct][r]*a_s;
        p_d[r] += acc[ct][r]*a_d;
      }
    }
    #pragma unroll
    for(int o = 1; o < 16; o <<= 1){
      #pragma unroll
      for(int r=0;r<4;r++){
        p_s[r] += __shfl_xor(p_s[r], o);
        p_d[r] += __shfl_xor(p_d[r], o);
      }
    }
    if(lr == 0){
      #pragma unroll
      for(int r=0;r<4;r++){
        int rr = orow0 + r;
        if(rr < M){ als[rr] = p_s[r]; ald[rr] = p_d[r]; }
      }
    }
  }
}

// ---------------- fused 4-head GAT aggregate: 4 wave-independent nodes per 256-thr block ----------------
// LDS-staged (decouples index loads from gathers) + next-chunk metadata prefetch in registers.
__global__ __launch_bounds__(256) void k_gat_agg4(
    const int* __restrict__ rp, const int* __restrict__ srcs, const u32x2* __restrict__ ed4,
    const bf16* __restrict__ hp,                 // [N,256]
    const float* __restrict__ als4, const float* __restrict__ ald4,
    const float* __restrict__ bias256, bf16* __restrict__ out1){
  const int wid = threadIdx.x >> 6, l = threadIdx.x & 63;
  const int n = blockIdx.x*4 + wid;
  if(n >= N_NODES) return;
  int eh = l >> 5, c8 = l & 31;
  int head = c8 >> 3;
  __shared__ int   ssrc_s[4][64];
  __shared__ float swt_s[4][64][4];
  int* ssrc = ssrc_s[wid];
  float (*swt)[4] = swt_s[wid];
  int s0 = rp[n], e0 = rp[n+1];
  if((unsigned)s0 > N_EDGES){ s0=0; e0=0; }
  if(e0 < s0 || (unsigned)e0 > N_EDGES) e0 = s0;
  float4 aldv = *(const float4*)&ald4[n*4];
  float4 alsvn = *(const float4*)&als4[n*4];
  float wsum[4] = {0.f,0.f,0.f,0.f};
  float dsum[4] = {0.f,0.f,0.f,0.f};
  float acc[8]  = {0.f,0.f,0.f,0.f,0.f,0.f,0.f,0.f};
  const unsigned short* hpu = (const unsigned short*)hp;

  int base = s0;
  int pm = min(64, e0 - base);
  int r_sn = 0; u32x2 r_e4; r_e4[0] = 0; r_e4[1] = 0;
  if(base < e0 && l < pm){
    r_sn = __builtin_nontemporal_load(&srcs[base+l]);
    r_e4 = __builtin_nontemporal_load(&ed4[base+l]);
  }
  while(base < e0){
    int m = pm;
    if(l < m){
      int sn = r_sn; if((unsigned)sn >= N_NODES) sn = 0;
      ssrc[l] = sn;
      float edf[4] = {us2f((unsigned short)(r_e4[0] & 0xffff)), us2f((unsigned short)(r_e4[0] >> 16)),
                      us2f((unsigned short)(r_e4[1] & 0xffff)), us2f((unsigned short)(r_e4[1] >> 16))};
      float4 alss = *(const float4*)&als4[sn*4];
      float alssv[4] = {alss.x, alss.y, alss.z, alss.w};
      float aldvv[4] = {aldv.x, aldv.y, aldv.z, aldv.w};
      float w4[4];
      #pragma unroll
      for(int h=0;h<4;h++){
        float sc = alssv[h] + aldvv[h] + edf[h];
        sc = sc > 0.f ? sc : NEG_SLOPE*sc;
        sc = fminf(sc, 30.f);
        float w = __expf(sc);
        w4[h] = w;
        wsum[h] += w; dsum[h] += edf[h];
      }
      *(float4*)&swt[l][0] = make_float4(w4[0], w4[1], w4[2], w4[3]);
    }
    wave_lds_fence();          // same-wave producer -> consumer; LDS per-wave in-order
    // prefetch next chunk's metadata; completes under the gather loop below
    int nbase = base + 64;
    pm = min(64, e0 - nbase);
    if(nbase < e0 && l < pm){
      r_sn = __builtin_nontemporal_load(&srcs[nbase+l]);
      r_e4 = __builtin_nontemporal_load(&ed4[nbase+l]);
    }
    #pragma unroll 8
    for(int i=0;i<m;i+=2){
      int j = i + eh;
      if(j < m){
        int row = ssrc[j];
        float w = swt[j][head];
        uint4 u = *(const uint4*)&hpu[(size_t)row*256 + 8*c8];
        acc8(acc, w, u);
      }
    }
    __builtin_amdgcn_wave_barrier();   // keep next-iter LDS writes below these reads
    base = nbase;
  }
  // butterfly wsum/dsum across 64 lanes; merge edge-parity halves of acc
  #pragma unroll
  for(int o=1;o<64;o<<=1){
    #pragma unroll
    for(int h=0;h<4;h++){
      wsum[h] += __shfl_xor(wsum[h], o);
      dsum[h] += __shfl_xor(dsum[h], o);
    }
  }
  #pragma unroll
  for(int q=0;q<8;q++) acc[q] += __shfl_xor(acc[q], 32);
  if(eh == 0){
    float alsnv[4] = {alsvn.x, alsvn.y, alsvn.z, alsvn.w};
    float aldnv[4] = {aldv.x, aldv.y, aldv.z, aldv.w};
    float sEh = sel4(wsum, head), sDh = sel4(dsum, head);
    float deg = (float)(e0 - s0);
    float sdot = deg > 0.f ? sDh/deg : 0.f;
    float sc = sel4(alsnv, head) + sel4(aldnv, head) + sdot;
    sc = sc > 0.f ? sc : NEG_SLOPE*sc;
    sc = fminf(sc, 30.f);
    float wself = __expf(sc);
    float self[8];
    unp8(self, *(const uint4*)&hpu[(size_t)n*256 + 8*c8]);
    float4 b0 = *(const float4*)&bias256[8*c8];
    float4 b1 = *(const float4*)&bias256[8*c8 + 4];
    float bi[8] = {b0.x,b0.y,b0.z,b0.w,b1.x,b1.y,b1.z,b1.w};
    float inv = 1.f/(sEh + wself);
    float o8[8];
    #pragma unroll
    for(int q=0;q<8;q++) o8[q] = (acc[q] + wself*self[q])*inv + bi[q];
    uint4 st;
    st.x = pk2(o8[0],o8[1]); st.y = pk2(o8[2],o8[3]);
    st.z = pk2(o8[4],o8[5]); st.w = pk2(o8[6],o8[7]);
    *(uint4*)&((unsigned short*)out1)[(size_t)n*256 + 8*c8] = st;
  }
}

// ---------------- single-head GAT aggregate: 4 wave-independent nodes per block ----------------
__global__ __launch_bounds__(256) void k_gat_agg1e(
    const int* __restrict__ rp, const int* __restrict__ srcs, const unsigned* __restrict__ ed1,
    const bf16* __restrict__ hp,                 // [N,64]
    const float* __restrict__ als, const float* __restrict__ ald,
    const float* __restrict__ bias64, bf16* __restrict__ out){
  const int wid = threadIdx.x >> 6, l = threadIdx.x & 63;
  const int n = blockIdx.x*4 + wid;
  if(n >= N_NODES) return;
  int eg = l >> 3, c8 = l & 7;
  __shared__ float sw_s[4][64];
  __shared__ int   ssrc_s[4][64];
  float* sw = sw_s[wid];
  int* ssrc = ssrc_s[wid];
  int s0 = rp[n], e0 = rp[n+1];
  if((unsigned)s0 > N_EDGES){ s0=0; e0=0; }
  if(e0 < s0 || (unsigned)e0 > N_EDGES) e0 = s0;
  float aldn = ald[n];
  float wsum_l = 0.f, dsum_l = 0.f;
  float acc[8] = {0.f,0.f,0.f,0.f,0.f,0.f,0.f,0.f};
  const unsigned short* hpu = (const unsigned short*)hp;
  int base = s0;
  int pm = min(64, e0 - base);
  int r_sn = 0; unsigned r_ew = 0;
  if(base < e0 && l < pm){
    r_sn = __builtin_nontemporal_load(&srcs[base+l]);
    r_ew = __builtin_nontemporal_load(&ed1[base+l]);
  }
  while(base < e0){
    int m = pm;
    if(l < m){
      int sn = r_sn; if((unsigned)sn >= N_NODES) sn = 0;
      ssrc[l] = sn;
      float ed = us2f((unsigned short)(r_ew & 0xffff));
      float sc = als[sn] + aldn + ed;
      sc = sc > 0.f ? sc : NEG_SLOPE*sc;
      sc = fminf(sc, 30.f);
      float w = __expf(sc);
      sw[l] = w;
      wsum_l += w; dsum_l += ed;
    }
    wave_lds_fence();
    int nbase = base + 64;
    pm = min(64, e0 - nbase);
    if(nbase < e0 && l < pm){
      r_sn = __builtin_nontemporal_load(&srcs[nbase+l]);
      r_ew = __builtin_nontemporal_load(&ed1[nbase+l]);
    }
    #pragma unroll 8
    for(int i=0;i<m;i+=8){
      int j = i + eg;
      if(j < m){
        int row = ssrc[j];
        float w = sw[j];
        uint4 u = *(const uint4*)&hpu[(size_t)row*64 + 8*c8];
        acc8(acc, w, u);
      }
    }
    __builtin_amdgcn_wave_barrier();
    base = nbase;
  }
  #pragma unroll
  for(int o=1;o<64;o<<=1){ wsum_l += __shfl_xor(wsum_l, o); dsum_l += __shfl_xor(dsum_l, o); }
  #pragma unroll
  for(int q=0;q<8;q++){
    acc[q] += __shfl_xor(acc[q], 8);
    acc[q] += __shfl_xor(acc[q], 16);
    acc[q] += __shfl_xor(acc[q], 32);
  }
  if(l < 8){
    float deg = (float)(e0 - s0);
    float sdot = deg > 0.f ? dsum_l/deg : 0.f;
    float sc = als[n] + aldn + sdot;
    sc = sc > 0.f ? sc : NEG_SLOPE*sc;
    sc = fminf(sc, 30.f);
    float wself = __expf(sc);
    float self[8];
    unp8(self, *(const uint4*)&hpu[(size_t)n*64 + 8*l]);
    float4 b0 = *(const float4*)&bias64[8*l];
    float4 b1 = *(const float4*)&bias64[8*l + 4];
    float bi[8] = {b0.x,b0.y,b0.z,b0.w,b1.x,b1.y,b1.z,b1.w};
    float inv = 1.f/(wsum_l + wself);
    float o8[8];
    #pragma unroll
    for(int q=0;q<8;q++) o8[q] = (acc[q] + wself*self[q])*inv + bi[q];
    uint4 st;
    st.x = pk2(o8[0],o8[1]); st.y = pk2(o8[2],o8[3]);
    st.z = pk2(o8[4],o8[5]); st.w = pk2(o8[6],o8[7]);
    *(uint4*)&((unsigned short*)out)[(size_t)n*64 + 8*l] = st;
  }
}

// ---------------- GCN aggregate: 4 wave-independent nodes per block ----------------
__global__ __launch_bounds__(256) void k_gcn_agg(
    const int* __restrict__ rp, const int* __restrict__ srcs,
    const float* __restrict__ dinv, const bf16* __restrict__ gp,
    const float* __restrict__ bias, bf16* __restrict__ out){
  const int wid = threadIdx.x >> 6, l = threadIdx.x & 63;
  const int n = blockIdx.x*4 + wid;
  if(n >= N_NODES) return;
  int eg = l >> 3, c8 = l & 7;
  __shared__ float sw_s[4][64];
  __shared__ int   ssrc_s[4][64];
  float* sw = sw_s[wid];
  int* ssrc = ssrc_s[wid];
  int s0 = rp[n], e0 = rp[n+1];
  if((unsigned)s0 > N_EDGES){ s0=0; e0=0; }
  if(e0 < s0 || (unsigned)e0 > N_EDGES) e0 = s0;
  float dn = dinv[n];
  float acc[8] = {0.f,0.f,0.f,0.f,0.f,0.f,0.f,0.f};
  const unsigned short* gpu = (const unsigned short*)gp;
  int base = s0;
  int pm = min(64, e0 - base);
  int r_sn = 0;
  if(base < e0 && l < pm){
    r_sn = __builtin_nontemporal_load(&srcs[base+l]);
  }
  while(base < e0){
    int m = pm;
    if(l < m){
      int sn = r_sn; if((unsigned)sn >= N_NODES) sn = 0;
      ssrc[l]=sn; sw[l]=dinv[sn];
    }
    wave_lds_fence();
    int nbase = base + 64;
    pm = min(64, e0 - nbase);
    if(nbase < e0 && l < pm){
      r_sn = __builtin_nontemporal_load(&srcs[nbase+l]);
    }
    #pragma unroll 8
    for(int i=0;i<m;i+=8){
      int j = i + eg;
      if(j < m){
        int row = ssrc[j];
        float w = sw[j];
        uint4 u = *(const uint4*)&gpu[(size_t)row*64 + 8*c8];
        acc8(acc, w, u);
      }
    }
    __builtin_amdgcn_wave_barrier();
    base = nbase;
  }
  #pragma unroll
  for(int q=0;q<8;q++){
    acc[q] += __shfl_xor(acc[q], 8);
    acc[q] += __shfl_xor(acc[q], 16);
    acc[q] += __shfl_xor(acc[q], 32);
  }
  if(l < 8){
    float self[8];
    unp8(self, *(const uint4*)&gpu[(size_t)n*64 + 8*l]);
    float4 b0 = *(const float4*)&bias[8*l];
    float4 b1 = *(const float4*)&bias[8*l + 4];
    float bi[8] = {b0.x,b0.y,b0.z,b0.w,b1.x,b1.y,b1.z,b1.w};
    float o8[8];
    #pragma unroll
    for(int q=0;q<8;q++) o8[q] = dn*(acc[q] + dn*self[q]) + bi[q];
    uint4 st;
    st.x = pk2(o8[0],o8[1]); st.y = pk2(o8[2],o8[3]);
    st.z = pk2(o8[4],o8[5]); st.w = pk2(o8[6],o8[7]);
    *(uint4*)&((unsigned short*)out)[(size_t)n*64 + 8*l] = st;
  }
}

// ---------------- BN stats (bf16 input) ----------------
template<int C>
__global__ void k_colstats(const bf16* __restrict__ X, float* __restrict__ sums){
  constexpr int RPB = 128;
  constexpr int RSTEP = 256 / C;
  int c = threadIdx.x % C;
  int r0 = threadIdx.x / C;
  int rbeg = blockIdx.x * RPB;
  int rend = min(N_NODES, rbeg + RPB);
  const unsigned short* Xu = (const unsigned short*)X;
  float s = 0.f, q = 0.f;
  for(int r = rbeg + r0; r < rend; r += RSTEP){
    float v = sane(us2f(Xu[(size_t)r*C + c]));
    s += v; q += v*v;
  }
  atomicAdd(&sums[c], s);
  atomicAdd(&sums[C + c], q);
}

// ---------------- mean pool with fused BN+ReLU (bf16 input), 64-row blocks ----------------
__global__ __launch_bounds__(64) void k_pool3(
    const bf16* __restrict__ h, const int* __restrict__ batch,
    const float* __restrict__ sums, const float* __restrict__ g4,
    const float* __restrict__ b4,
    float* __restrict__ psum, float* __restrict__ pcnt){
  int t = threadIdx.x;
  int n0 = blockIdx.x * 64;
  int n1 = min(N_NODES, n0 + 64);
  if(n0 >= n1) return;
  const float invN = 1.0f / (float)N_NODES;
  float mean = sums[t]*invN;
  float var = fmaxf(sums[64+t]*invN - mean*mean, 0.f);
  float rstd = rsqrtf(var + BN_EPS);
  float gg = g4[t], bb = b4[t];
  const unsigned short* hu = (const unsigned short*)h;
  int cur = batch[n0]; if((unsigned)cur >= N_GRAPHS) cur = 0;
  float acc = 0.f; int cl = 0;
  for(int n = n0; n < n1; n++){
    int g = batch[n]; if((unsigned)g >= N_GRAPHS) g = 0;
    if(g != cur){
      atomicAdd(&psum[cur*64 + t], acc);
      if(t == 0) atomicAdd(&pcnt[cur], (float)cl);
      acc = 0.f; cl = 0; cur = g;
    }
    float y = (sane(us2f(hu[(size_t)n*64 + t]))-mean)*rstd*gg + bb;
    acc += fmaxf(y, 0.f);
    cl++;
  }
  atomicAdd(&psum[cur*64 + t], acc);
  if(t == 0) atomicAdd(&pcnt[cur], (float)cl);
}

// ---------------- head MLPs + output ----------------
__device__ __forceinline__ void stO(void* o, size_t i, float v, int m){
  if(m) ((float*)o)[i] = v; else ((bf16*)o)[i] = f2b(v);
}

__global__ __launch_bounds__(128) void k_head(
    const float* __restrict__ psum, const float* __restrict__ pcnt,
    const float* __restrict__ exf,
    const float* __restrict__ Wex1, const float* __restrict__ bex1,
    const float* __restrict__ Wex2, const float* __restrict__ bex2,
    const float* __restrict__ Wc1, const float* __restrict__ bc1,
    const float* __restrict__ Wc2, const float* __restrict__ bc2,
    const void* __restrict__ xdet, void* __restrict__ dout){
  int m0 = detect_mode_block(xdet);
  int g = blockIdx.x; int t = threadIdx.x;
  __shared__ float ci[128];
  __shared__ float e1[64];
  __shared__ float comb[128];
  __shared__ float red[128];
  if(t < 64){
    float c = fmaxf(pcnt[g], 1.f);
    float xp = sane(psum[g*64 + t]) / c;
    ci[t] = xp;
    stO(dout, 256 + (size_t)g*64 + t, xp, m0);
  } else {
    int j = t - 64;
    float s = bex1[j];
    for(int k=0;k<32;k++) s += exf[g*32 + k] * Wex1[k*64 + j];
    e1[j] = fmaxf(s, 0.f);
  }
  __syncthreads();
  if(t >= 64){
    int j = t - 64;
    float s = bex2[j];
    for(int k=0;k<64;k++) s += e1[k] * Wex2[k*64 + j];
    ci[64 + j] = fmaxf(s, 0.f);
  }
  __syncthreads();
  {
    float s = bc1[t];
    for(int k=0;k<128;k++) s += ci[k] * Wc1[k*128 + t];
    s = fmaxf(s, 0.f);
    comb[t] = s;
    stO(dout, 256 + 16384 + (size_t)g*128 + t, s, m0);
  }
  __syncthreads();
  red[t] = comb[t] * Wc2[t];
  __syncthreads();
  for(int o=64;o>0;o>>=1){ if(t<o) red[t]+=red[t+o]; __syncthreads(); }
  if(t==0) stO(dout, g, red[0] + bc2[0], m0);
}

// ---------------- launch ----------------
extern "C" void kernel_launch(void* const* d_in, const int* in_sizes, int n_in,
                              void* d_out, int out_size, void* d_ws, size_t ws_size,
                              hipStream_t stream){
  const void* x    = d_in[0];
  const void* ea   = d_in[1];
  const int* ei    = (const int*)d_in[3];
  const int* batch = (const int*)d_in[4];
  const int* src = ei;
  const int* dst = ei + N_EDGES;

  char* base = (char*)d_ws;
  size_t off = 0;
  auto alloc = [&](size_t bytes) -> void* {
    void* r = base + off;
    off += (bytes + 255) & ~(size_t)255;
    return r;
  };
  int*   cnt    = (int*)  alloc((size_t)N_NODES*4);
  int*   fill   = (int*)  alloc((size_t)N_NODES*4);
  float* bnstat = (float*)alloc(4096);
  float* pool   = (float*)alloc((size_t)(N_GRAPHS*64 + N_GRAPHS)*4);
  size_t zbytes = off;
  int*   rp      = (int*)  alloc((size_t)(N_NODES+1)*4);
  int*   bsum    = (int*)  alloc(256*4);
  int*   srcs    = (int*)  alloc((size_t)N_EDGES*4);
  u32x2* ed4     = (u32x2*)alloc((size_t)N_EDGES*8);
  unsigned* ed1  = (unsigned*)alloc((size_t)N_EDGES*4);
  float* dinv    = (float*)alloc((size_t)N_NODES*4);
  float* w_e     = (float*)alloc(64*4);
  float* als4    = (float*)alloc((size_t)N_NODES*4*4);
  float* ald4    = (float*)alloc((size_t)N_NODES*4*4);
  float* wbank   = (float*)alloc(80000*4);
  bf16*  wt      = (bf16*) alloc((size_t)40960*2);         // transposed bf16 weights
  bf16*  hp      = (bf16*) alloc((size_t)N_NODES*256*2);
  bf16*  outb    = (bf16*) alloc((size_t)N_NODES*256*2);   // bf16 activations

  bf16* out1 = outb;
  bf16* out2 = outb;                             // aliases (previous dead)
  bf16* out3 = outb + (size_t)N_NODES*64;
  bf16* out4 = outb + (size_t)N_NODES*128;
  float* bn1 = bnstat;
  float* bn2 = bnstat + 512;
  float* bn3 = bnstat + 640;
  float* bn4 = bnstat + 768;
  float* psum = pool;
  float* pcnt = pool + N_GRAPHS*64;

  bf16* wt1  = wt;            // [256][64]
  bf16* wt2  = wt + 16384;    // [64][256]
  bf16* wtg1 = wt + 32768;    // [64][64]
  bf16* wtg2 = wt + 36864;    // [64][64]

  const int segidx[NSEG] = {2, 5,6,7,8,9,10,11,12, 13,14,15,16,17,18,19,20,
                            21,22,23,24, 25,26,27,28, 29,30,31,32, 33,34,35,36};
  const int segn[NSEG] = {8192, 16384,256,256,2048,256,256,256,256,
                          16384,64,64,512,64,64,64,64,
                          4096,64,64,64, 4096,64,64,64,
                          2048,64,4096,64, 16384,128,128,1};
  Bank bk;
  int offs[NSEG]; int acc0 = 0;
  for(int i=0;i<NSEG;i++){ bk.p[i]=d_in[segidx[i]]; bk.n[i]=segn[i]; bk.off[i]=acc0; offs[i]=acc0; acc0+=segn[i]; }
  const float* f_exf = wbank + offs[0];
  const float* fas1 = wbank+offs[2]; const float* fad1 = wbank+offs[3];
  const float* fb1  = wbank+offs[6];
  const float* fg1 = wbank+offs[7]; const float* fbe1 = wbank+offs[8];
  const float* fas2 = wbank+offs[10]; const float* fad2 = wbank+offs[11];
  const float* fb2 = wbank+offs[14];
  const float* fg2 = wbank+offs[15]; const float* fbe2 = wbank+offs[16];
  const float* fbg1 = wbank+offs[18]; const float* fg3 = wbank+offs[19];
  const float* fbe3= wbank+offs[20];
  const float* fbg2 = wbank+offs[22]; const float* fg4 = wbank+offs[23];
  const float* fbe4= wbank+offs[24];
  const float* fWex1=wbank+offs[25]; const float* fbex1= wbank+offs[26];
  const float* fWex2=wbank+offs[27]; const float* fbex2= wbank+offs[28];
  const float* fWc1= wbank+offs[29]; const float* fbc1 = wbank+offs[30];
  const float* fWc2= wbank+offs[31]; const float* fbc2 = wbank+offs[32];

  const int nbN  = (N_NODES + 255)/256;
  const int nbE2 = (N_EDGES + 511)/512;  // fill: 2 edges/thread
  const int nbT  = (N_NODES + 63)/64;
  const int nbA  = (N_NODES + 3)/4;      // 4 wave-independent nodes per block
  const int nbP  = (N_NODES + 63)/64;    // pool blocks (64 rows each)

  hipMemsetAsync(d_ws, 0, zbytes, stream);
  // mega prep: count(4 edges/thr) | convert | wt(raw) | we(raw)
  k_prep<<<PREP_COUNT + PREP_CONV + PREP_WT + 1, 256, 0, stream>>>(
      bk, x, dst, cnt, wbank, wt,
      d_in[5], d_in[13], d_in[21], d_in[25],
      d_in[8], d_in[9], d_in[16], d_in[17], w_e);
  k_blocksum<<<nbN,256,0,stream>>>(cnt, bsum);
  k_scan_write<<<nbN,256,0,stream>>>(cnt, bsum, rp, dinv, nbN);
  k_fill<<<nbE2,256,0,stream>>>(src, dst, rp, fill, ea, x, w_e, srcs, ed4, ed1);

  // GAT layer 1 (MFMA on raw x + fused alpha dots -> aggregate)
  k_gemmA_mfma<<<nbT,256,0,stream>>>(x, wt1, hp, N_NODES, fas1, fad1, als4, ald4);
  k_gat_agg4<<<nbA,256,0,stream>>>(rp, srcs, ed4, hp, als4, ald4, fb1, out1);
  k_colstats<256><<<(N_NODES+127)/128,256,0,stream>>>(out1, bn1);

  // GAT layer 2 (1 head) — BN1+ReLU + alpha dots fused into MFMA
  k_gemmB_mfma<256><<<nbT,256,0,stream>>>(out1, wt2, hp, N_NODES, bn1, fg1, fbe1,
                                          fas2, fad2, als4, ald4);
  k_gat_agg1e<<<nbA,256,0,stream>>>(rp, srcs, ed1, hp, als4, ald4, fb2, out2);
  k_colstats<64><<<(N_NODES+127)/128,256,0,stream>>>(out2, bn2);

  // GCN layer 1 — BN2+ReLU fused
  k_gemmB_mfma<64><<<nbT,256,0,stream>>>(out2, wtg1, hp, N_NODES, bn2, fg2, fbe2,
                                         nullptr, nullptr, nullptr, nullptr);
  k_gcn_agg<<<nbA,256,0,stream>>>(rp, srcs, dinv, hp, fbg1, out3);
  k_colstats<64><<<(N_NODES+127)/128,256,0,stream>>>(out3, bn3);

  // GCN layer 2 — BN3+ReLU fused
  k_gemmB_mfma<64><<<nbT,256,0,stream>>>(out3, wtg2, hp, N_NODES, bn3, fg3, fbe3,
                                         nullptr, nullptr, nullptr, nullptr);
  k_gcn_agg<<<nbA,256,0,stream>>>(rp, srcs, dinv, hp, fbg2, out4);
  k_colstats<64><<<(N_NODES+127)/128,256,0,stream>>>(out4, bn4);

  // pool (BN4+ReLU fused) + head
  k_pool3<<<nbP,64,0,stream>>>(out4, batch, bn4, fg4, fbe4, psum, pcnt);
  k_head<<<N_GRAPHS,128,0,stream>>>(psum, pcnt, f_exf, fWex1, fbex1, fWex2, fbex2,
                                    fWc1, fbc1, fWc2, fbc2, x, (void*)d_out);
}

// Round 11
// 874.482 us; speedup vs baseline: 1.0208x; 1.0208x over previous
//
#include <hip/hip_runtime.h>
#include <hip/hip_bf16.h>

#define N_NODES 50000
#define N_EDGES 1600000
#define N_GRAPHS 256
#define NEG_SLOPE 0.2f
#define BN_EPS 1e-5f

typedef __hip_bfloat16 bf16;
typedef __attribute__((ext_vector_type(8))) short s16x8;   // 8 bf16 in 4 VGPRs
typedef __attribute__((ext_vector_type(4))) float f32x4;
typedef __attribute__((ext_vector_type(2))) unsigned u32x2;

__device__ __forceinline__ float b2f(bf16 v){ return __bfloat162float(v); }
__device__ __forceinline__ bf16 f2b(float v){ return __float2bfloat16(v); }
__device__ __forceinline__ float us2f(unsigned short u){ return __uint_as_float(((unsigned)u)<<16); }
__device__ __forceinline__ unsigned short f2us(float v){ bf16 b = f2b(v); return *(unsigned short*)&b; }
__device__ __forceinline__ unsigned pk2(float a, float b){ return (unsigned)f2us(a) | ((unsigned)f2us(b)<<16); }
__device__ __forceinline__ float ldF(const void* p, size_t i, int m){
  return m ? ((const float*)p)[i] : b2f(((const bf16*)p)[i]);
}
__device__ __forceinline__ float sane(float v){
  return (v == v && fabsf(v) < 1e30f) ? v : 0.f;
}
__device__ __forceinline__ float sel4(const float v[4], int h){
  float r = v[0];
  r = (h==1) ? v[1] : r;
  r = (h==2) ? v[2] : r;
  r = (h==3) ? v[3] : r;
  return r;
}
// acc[0..7] += w * (8 bf16 packed in uint4)
__device__ __forceinline__ void acc8(float* acc, float w, uint4 u){
  acc[0] += w*us2f((unsigned short)(u.x & 0xffff)); acc[1] += w*us2f((unsigned short)(u.x >> 16));
  acc[2] += w*us2f((unsigned short)(u.y & 0xffff)); acc[3] += w*us2f((unsigned short)(u.y >> 16));
  acc[4] += w*us2f((unsigned short)(u.z & 0xffff)); acc[5] += w*us2f((unsigned short)(u.z >> 16));
  acc[6] += w*us2f((unsigned short)(u.w & 0xffff)); acc[7] += w*us2f((unsigned short)(u.w >> 16));
}
__device__ __forceinline__ void unp8(float* o, uint4 u){
  o[0] = us2f((unsigned short)(u.x & 0xffff)); o[1] = us2f((unsigned short)(u.x >> 16));
  o[2] = us2f((unsigned short)(u.y & 0xffff)); o[3] = us2f((unsigned short)(u.y >> 16));
  o[4] = us2f((unsigned short)(u.z & 0xffff)); o[5] = us2f((unsigned short)(u.z >> 16));
  o[6] = us2f((unsigned short)(u.w & 0xffff)); o[7] = us2f((unsigned short)(u.w >> 16));
}
__device__ __forceinline__ s16x8 pk8(const float* v){
  s16x8 r;
  #pragma unroll
  for(int j=0;j<8;j++) r[j] = (short)f2us(v[j]);
  return r;
}
// wave-internal LDS fence: all prior ds_writes complete + no compiler reordering
__device__ __forceinline__ void wave_lds_fence(){
  __builtin_amdgcn_sched_barrier(0);
  asm volatile("s_waitcnt lgkmcnt(0)" ::: "memory");
  __builtin_amdgcn_sched_barrier(0);
}

// block-level dtype detection
__device__ int detect_mode_block(const void* x){
  __shared__ int s_ins;
  if(threadIdx.x == 0) s_ins = 0;
  __syncthreads();
  const unsigned short* u = (const unsigned short*)x;
  int c = 0;
  for(int i = threadIdx.x; i < 1024; i += blockDim.x){
    float v = fabsf(us2f(u[i]));
    if(!(v > 1e-6f && v < 1e4f)) c++;
  }
  if(c) atomicAdd(&s_ins, c);
  __syncthreads();
  return (s_ins > 128) ? 1 : 0;   // 1 => f32
}

// ---------------- weight bank layout ----------------
#define NSEG 33
struct Bank { const void* p[NSEG]; int n[NSEG]; int off[NSEG]; };

// ---------------- mega prep kernel: count | convert | wt | we (all independent) ----------------
#define PREP_COUNT 6250
#define PREP_CONV  (64*NSEG)
#define PREP_WT    160
__global__ void k_prep(Bank bk, const void* xdet, const int* __restrict__ dst,
                       int* __restrict__ cnt, float* __restrict__ wbank,
                       bf16* __restrict__ wt,
                       const void* pW1, const void* pW2, const void* pWg1, const void* pWg2,
                       const void* pWe1, const void* pae1, const void* pWe2, const void* pae2,
                       float* __restrict__ w_e){
  int bid = blockIdx.x;
  int t = threadIdx.x;
  if(bid < PREP_COUNT){
    int e = bid*256 + t;
    if(e < N_EDGES){
      int d = dst[e]; if((unsigned)d >= N_NODES) d = 0;
      atomicAdd(&cnt[d], 1);
    }
    return;
  }
  int m = detect_mode_block(xdet);
  if(bid < PREP_COUNT + PREP_CONV){
    int b2 = bid - PREP_COUNT;
    int seg = b2 >> 6;
    int i = (b2 & 63)*256 + t;
    if(i < bk.n[seg]) wbank[bk.off[seg] + i] = ldF(bk.p[seg], i, m);
  } else if(bid < PREP_COUNT + PREP_CONV + PREP_WT){
    int i = (bid - PREP_COUNT - PREP_CONV)*256 + t;
    // wt layout: [0,16384) Wt1[256][64]; [16384,32768) Wt2[64][256]; then Wtg1,Wtg2 [64][64]
    if(i < 16384){
      int c = i >> 6, k = i & 63;
      wt[i] = f2b(ldF(pW1, k*256 + c, m));
    } else if(i < 32768){
      int j = i - 16384; int c = j >> 8, k = j & 255;
      wt[i] = f2b(ldF(pW2, k*64 + c, m));
    } else if(i < 36864){
      int j = i - 32768; int c = j >> 6, k = j & 63;
      wt[i] = f2b(ldF(pWg1, k*64 + c, m));
    } else if(i < 40960){
      int j = i - 36864; int c = j >> 6, k = j & 63;
      wt[i] = f2b(ldF(pWg2, k*64 + c, m));
    }
  } else {
    if(t < 32){
      int h = t >> 3, k = t & 7;
      float s = 0.f;
      for(int d=0;d<64;d++) s += ldF(pWe1, k*256 + h*64 + d, m) * ldF(pae1, h*64 + d, m);
      w_e[t] = s;
    } else if(t < 40){
      int k = t - 32;
      float s = 0.f;
      for(int d=0;d<64;d++) s += ldF(pWe2, k*64 + d, m) * ldF(pae2, d, m);
      w_e[t] = s;
    }
  }
}

// ---------------- CSR build ----------------
__global__ void k_blocksum(const int* __restrict__ cnt, int* __restrict__ bsum){
  __shared__ int s[256];
  int i = blockIdx.x*256 + threadIdx.x;
  s[threadIdx.x] = (i < N_NODES) ? cnt[i] : 0;
  __syncthreads();
  for(int o=128;o>0;o>>=1){ if(threadIdx.x<o) s[threadIdx.x]+=s[threadIdx.x+o]; __syncthreads(); }
  if(threadIdx.x==0) bsum[blockIdx.x]=s[0];
}

// scan over bsum inlined (nb <= 256), then per-block scan of cnt
__global__ void k_scan_write(const int* __restrict__ cnt, const int* __restrict__ bsum,
                             int* __restrict__ rp, float* __restrict__ dinv, int nb){
  __shared__ int sb[256];
  __shared__ int s[256];
  int t = threadIdx.x; int i = blockIdx.x*256 + t;
  sb[t] = (t<nb) ? bsum[t] : 0;
  __syncthreads();
  for(int o=1;o<256;o<<=1){ int v=(t>=o)?sb[t-o]:0; __syncthreads(); sb[t]+=v; __syncthreads(); }
  int bofs = (blockIdx.x==0) ? 0 : sb[blockIdx.x-1];
  int v = (i<N_NODES) ? cnt[i] : 0;
  s[t]=v; __syncthreads();
  for(int o=1;o<256;o<<=1){ int a=(t>=o)?s[t-o]:0; __syncthreads(); s[t]+=a; __syncthreads(); }
  if(i<N_NODES){
    rp[i+1] = s[t] + bofs;
    dinv[i] = rsqrtf((float)v + 1.f);
  }
  if(i==0) rp[0]=0;
}

// fill CSR (SoA): srcs[slot] 4B, ed4[slot] 8B (4 bf16), ed1[slot] 4B (1 bf16 in low16)
// Plain stores (NOT nontemporal): slots are dense, so same-sector stores from
// different edges merge in L2 before writeback (round-6 post-mortem: nt scatter = 200 MB writeback).
__global__ void k_fill(const int* __restrict__ src, const int* __restrict__ dst,
                       const int* __restrict__ rp, int* __restrict__ fill,
                       const void* __restrict__ ea, const void* __restrict__ xdet,
                       const float* __restrict__ w_e,
                       int* __restrict__ srcs, u32x2* __restrict__ ed4,
                       unsigned* __restrict__ ed1){
  int m = detect_mode_block(xdet);
  int e = blockIdx.x*256 + threadIdx.x;
  if(e >= N_EDGES) return;
  int d = dst[e]; if((unsigned)d >= N_NODES) d = 0;
  int p = atomicAdd(&fill[d], 1);
  int slot = rp[d] + p;
  if((unsigned)slot >= N_EDGES) return;
  int sv = src[e]; if((unsigned)sv >= N_NODES) sv = 0;
  float a[8];
  if(m){
    const float* eaf = (const float*)ea;
    float4 lo = *(const float4*)&eaf[(size_t)e*8];
    float4 hi = *(const float4*)&eaf[(size_t)e*8 + 4];
    a[0]=lo.x; a[1]=lo.y; a[2]=lo.z; a[3]=lo.w;
    a[4]=hi.x; a[5]=hi.y; a[6]=hi.z; a[7]=hi.w;
  } else {
    #pragma unroll
    for(int k=0;k<8;k++) a[k] = b2f(((const bf16*)ea)[(size_t)e*8 + k]);
  }
  unsigned d4[4];
  #pragma unroll
  for(int h=0;h<4;h++){
    float s = 0.f;
    #pragma unroll
    for(int k=0;k<8;k++) s += a[k]*w_e[h*8+k];
    d4[h] = f2us(s);
  }
  float s1 = 0.f;
  #pragma unroll
  for(int k=0;k<8;k++) s1 += a[k]*w_e[32+k];
  srcs[slot] = sv;
  u32x2 e4;
  e4[0] = d4[0] | (d4[1] << 16);
  e4[1] = d4[2] | (d4[3] << 16);
  ed4[slot] = e4;
  ed1[slot] = (unsigned)f2us(s1);
}

// ---------------- MFMA GEMM layer 1: raw x [M,64] x wt1 -> hp [M,256] bf16 + fused alpha dots ----------------
__global__ __launch_bounds__(256) void k_gemmA_mfma(
    const void* __restrict__ x,       // raw input, bf16 or f32 (mode-detected)
    const bf16* __restrict__ wt1,     // [256][64] = Wt1[col][k]
    bf16* __restrict__ hp, int M,
    const float* __restrict__ asrc,   // [256]
    const float* __restrict__ adst,   // [256]
    float* __restrict__ als4, float* __restrict__ ald4)
{
  int m = detect_mode_block(x);
  const int tid = threadIdx.x;
  const int w = tid >> 6, l = tid & 63;
  const int lr = l & 15, lg = l >> 4;
  const int bm = blockIdx.x*64 + w*16;
  const int row = min(bm + lr, M-1);
  s16x8 a0, a1;
  if(m){
    const float* ar = (const float*)x + (size_t)row*64;
    float va[8], vb[8];
    #pragma unroll
    for(int j=0;j<8;j++){ va[j] = ar[8*lg + j]; vb[j] = ar[32 + 8*lg + j]; }
    a0 = pk8(va); a1 = pk8(vb);
  } else {
    const uint4* ar = (const uint4*)((const bf16*)x + (size_t)row*64);
    uint4 a0u = ar[lg];
    uint4 a1u = ar[4 + lg];
    a0 = *(s16x8*)&a0u; a1 = *(s16x8*)&a1u;
  }
  unsigned short* out = (unsigned short*)hp;
  const int orow0 = bm + lg*4;
  float p_s[4][4] = {};   // [head][r]
  float p_d[4][4] = {};
  #pragma unroll
  for(int ct = 0; ct < 16; ct++){
    const uint4* brow = (const uint4*)(wt1 + (size_t)(ct*16 + lr)*64);
    uint4 b0u = brow[lg];
    uint4 b1u = brow[4 + lg];
    f32x4 acc = {0.f, 0.f, 0.f, 0.f};
    acc = __builtin_amdgcn_mfma_f32_16x16x32_bf16(a0, *(s16x8*)&b0u, acc, 0, 0, 0);
    acc = __builtin_amdgcn_mfma_f32_16x16x32_bf16(a1, *(s16x8*)&b1u, acc, 0, 0, 0);
    float a_s = asrc[ct*16 + lr];
    float a_d = adst[ct*16 + lr];
    int hh = ct >> 2;
    #pragma unroll
    for(int r = 0; r < 4; r++){
      p_s[hh][r] += acc[r]*a_s;
      p_d[hh][r] += acc[r]*a_d;
      int rr = orow0 + r;
      if(rr < M) out[(size_t)rr*256 + ct*16 + lr] = f2us(acc[r]);
    }
  }
  #pragma unroll
  for(int o = 1; o < 16; o <<= 1){
    #pragma unroll
    for(int hh=0; hh<4; hh++)
      #pragma unroll
      for(int r=0; r<4; r++){
        p_s[hh][r] += __shfl_xor(p_s[hh][r], o);
        p_d[hh][r] += __shfl_xor(p_d[hh][r], o);
      }
  }
  if(lr == 0){
    #pragma unroll
    for(int r=0;r<4;r++){
      int rr = orow0 + r;
      if(rr < M){
        #pragma unroll
        for(int hh=0;hh<4;hh++){
          als4[rr*4 + hh] = p_s[hh][r];
          ald4[rr*4 + hh] = p_d[hh][r];
        }
      }
    }
  }
}

// ---------------- MFMA GEMM layers 2-4 (optional fused single-head alpha dots) ----------------
template<int KIN>
__global__ __launch_bounds__(256) void k_gemmB_mfma(
    const bf16* __restrict__ A, const bf16* __restrict__ Wt,
    bf16* __restrict__ C, int M,
    const float* __restrict__ bnsums, const float* __restrict__ bng, const float* __restrict__ bnb,
    const float* __restrict__ asrc, const float* __restrict__ adst,
    float* __restrict__ als, float* __restrict__ ald)
{
  __shared__ float st_s[KIN];
  __shared__ float st_t[KIN];
  const int tid = threadIdx.x;
  if(tid < KIN){
    const float invN = 1.0f / (float)N_NODES;
    float mean = bnsums[tid]*invN;
    float var  = fmaxf(bnsums[KIN+tid]*invN - mean*mean, 0.f);
    float s = bng[tid]*rsqrtf(var + BN_EPS);
    st_s[tid] = s;
    st_t[tid] = bnb[tid] - mean*s;
  }
  __syncthreads();
  const int w = tid >> 6, l = tid & 63;
  const int lr = l & 15, lg = l >> 4;
  const int bm = blockIdx.x*64 + w*16;
  const int arow_i = bm + lr;
  const uint4* arow = (const uint4*)(A + (size_t)min(arow_i, M-1)*KIN);
  f32x4 acc[4];
  #pragma unroll
  for(int ct=0;ct<4;ct++) acc[ct] = (f32x4){0.f,0.f,0.f,0.f};
  #pragma unroll
  for(int k0 = 0; k0 < KIN; k0 += 32){
    uint4 au = arow[(k0 >> 3) + lg];          // elems k0 + 8*lg .. +7
    int c0 = k0 + lg*8;
    float v[8]; unp8(v, au);
    #pragma unroll
    for(int j = 0; j < 8; j++){
      float y = sane(v[j])*st_s[c0+j] + st_t[c0+j];
      v[j] = fmaxf(y, 0.f);
    }
    s16x8 af = pk8(v);
    #pragma unroll
    for(int ct = 0; ct < 4; ct++){
      const uint4* brow = (const uint4*)(Wt + (size_t)(ct*16 + lr)*KIN);
      uint4 bu = brow[(k0 >> 3) + lg];
      acc[ct] = __builtin_amdgcn_mfma_f32_16x16x32_bf16(af, *(s16x8*)&bu, acc[ct], 0, 0, 0);
    }
  }
  unsigned short* out = (unsigned short*)C;
  const int orow0 = bm + lg*4;
  #pragma unroll
  for(int ct = 0; ct < 4; ct++){
    #pragma unroll
    for(int r = 0; r < 4; r++){
      int rr = orow0 + r;
      if(rr < M) out[(size_t)rr*64 + ct*16 + lr] = f2us(acc[ct][r]);
    }
  }
  if(als){
    float p_s[4] = {0.f,0.f,0.f,0.f};
    float p_d[4] = {0.f,0.f,0.f,0.f};
    #pragma unroll
    for(int ct=0;ct<4;ct++){
      float a_s = asrc[ct*16 + lr];
      float a_d = adst[ct*16 + lr];
      #pragma unroll
      for(int r=0;r<4;r++){
        p_s[r] += acc[ct][r]*a_s;
        p_d[r] += acc[ct][r]*a_d;
      }
    }
    #pragma unroll
    for(int o = 1; o < 16; o <<= 1){
      #pragma unroll
      for(int r=0;r<4;r++){
        p_s[r] += __shfl_xor(p_s[r], o);
        p_d[r] += __shfl_xor(p_d[r], o);
      }
    }
    if(lr == 0){
      #pragma unroll
      for(int r=0;r<4;r++){
        int rr = orow0 + r;
        if(rr < M){ als[rr] = p_s[r]; ald[rr] = p_d[r]; }
      }
    }
  }
}

// ---------------- fused 4-head GAT aggregate: 4 wave-independent nodes per 256-thr block ----------------
// LDS-staged (decouples index loads from gathers) + next-chunk metadata prefetch in registers.
__global__ __launch_bounds__(256) void k_gat_agg4(
    const int* __restrict__ rp, const int* __restrict__ srcs, const u32x2* __restrict__ ed4,
    const bf16* __restrict__ hp,                 // [N,256]
    const float* __restrict__ als4, const float* __restrict__ ald4,
    const float* __restrict__ bias256, bf16* __restrict__ out1){
  const int wid = threadIdx.x >> 6, l = threadIdx.x & 63;
  const int n = blockIdx.x*4 + wid;
  if(n >= N_NODES) return;
  int eh = l >> 5, c8 = l & 31;
  int head = c8 >> 3;
  __shared__ int   ssrc_s[4][64];
  __shared__ float swt_s[4][64][4];
  int* ssrc = ssrc_s[wid];
  float (*swt)[4] = swt_s[wid];
  int s0 = rp[n], e0 = rp[n+1];
  if((unsigned)s0 > N_EDGES){ s0=0; e0=0; }
  if(e0 < s0 || (unsigned)e0 > N_EDGES) e0 = s0;
  float4 aldv = *(const float4*)&ald4[n*4];
  float4 alsvn = *(const float4*)&als4[n*4];
  float wsum[4] = {0.f,0.f,0.f,0.f};
  float dsum[4] = {0.f,0.f,0.f,0.f};
  float acc[8]  = {0.f,0.f,0.f,0.f,0.f,0.f,0.f,0.f};
  const unsigned short* hpu = (const unsigned short*)hp;

  int base = s0;
  int pm = min(64, e0 - base);
  int r_sn = 0; u32x2 r_e4; r_e4[0] = 0; r_e4[1] = 0;
  if(base < e0 && l < pm){
    r_sn = __builtin_nontemporal_load(&srcs[base+l]);
    r_e4 = __builtin_nontemporal_load(&ed4[base+l]);
  }
  while(base < e0){
    int m = pm;
    if(l < m){
      int sn = r_sn; if((unsigned)sn >= N_NODES) sn = 0;
      ssrc[l] = sn;
      float edf[4] = {us2f((unsigned short)(r_e4[0] & 0xffff)), us2f((unsigned short)(r_e4[0] >> 16)),
                      us2f((unsigned short)(r_e4[1] & 0xffff)), us2f((unsigned short)(r_e4[1] >> 16))};
      float4 alss = *(const float4*)&als4[sn*4];
      float alssv[4] = {alss.x, alss.y, alss.z, alss.w};
      float aldvv[4] = {aldv.x, aldv.y, aldv.z, aldv.w};
      float w4[4];
      #pragma unroll
      for(int h=0;h<4;h++){
        float sc = alssv[h] + aldvv[h] + edf[h];
        sc = sc > 0.f ? sc : NEG_SLOPE*sc;
        sc = fminf(sc, 30.f);
        float w = __expf(sc);
        w4[h] = w;
        wsum[h] += w; dsum[h] += edf[h];
      }
      *(float4*)&swt[l][0] = make_float4(w4[0], w4[1], w4[2], w4[3]);
    }
    wave_lds_fence();          // same-wave producer -> consumer; LDS per-wave in-order
    // prefetch next chunk's metadata; completes under the gather loop below
    int nbase = base + 64;
    pm = min(64, e0 - nbase);
    if(nbase < e0 && l < pm){
      r_sn = __builtin_nontemporal_load(&srcs[nbase+l]);
      r_e4 = __builtin_nontemporal_load(&ed4[nbase+l]);
    }
    #pragma unroll 8
    for(int i=0;i<m;i+=2){
      int j = i + eh;
      if(j < m){
        int row = ssrc[j];
        float w = swt[j][head];
        uint4 u = *(const uint4*)&hpu[(size_t)row*256 + 8*c8];
        acc8(acc, w, u);
      }
    }
    __builtin_amdgcn_wave_barrier();   // keep next-iter LDS writes below these reads
    base = nbase;
  }
  // butterfly wsum/dsum across 64 lanes; merge edge-parity halves of acc
  #pragma unroll
  for(int o=1;o<64;o<<=1){
    #pragma unroll
    for(int h=0;h<4;h++){
      wsum[h] += __shfl_xor(wsum[h], o);
      dsum[h] += __shfl_xor(dsum[h], o);
    }
  }
  #pragma unroll
  for(int q=0;q<8;q++) acc[q] += __shfl_xor(acc[q], 32);
  if(eh == 0){
    float alsnv[4] = {alsvn.x, alsvn.y, alsvn.z, alsvn.w};
    float aldnv[4] = {aldv.x, aldv.y, aldv.z, aldv.w};
    float sEh = sel4(wsum, head), sDh = sel4(dsum, head);
    float deg = (float)(e0 - s0);
    float sdot = deg > 0.f ? sDh/deg : 0.f;
    float sc = sel4(alsnv, head) + sel4(aldnv, head) + sdot;
    sc = sc > 0.f ? sc : NEG_SLOPE*sc;
    sc = fminf(sc, 30.f);
    float wself = __expf(sc);
    float self[8];
    unp8(self, *(const uint4*)&hpu[(size_t)n*256 + 8*c8]);
    float4 b0 = *(const float4*)&bias256[8*c8];
    float4 b1 = *(const float4*)&bias256[8*c8 + 4];
    float bi[8] = {b0.x,b0.y,b0.z,b0.w,b1.x,b1.y,b1.z,b1.w};
    float inv = 1.f/(sEh + wself);
    float o8[8];
    #pragma unroll
    for(int q=0;q<8;q++) o8[q] = (acc[q] + wself*self[q])*inv + bi[q];
    uint4 st;
    st.x = pk2(o8[0],o8[1]); st.y = pk2(o8[2],o8[3]);
    st.z = pk2(o8[4],o8[5]); st.w = pk2(o8[6],o8[7]);
    *(uint4*)&((unsigned short*)out1)[(size_t)n*256 + 8*c8] = st;
  }
}

// ---------------- single-head GAT aggregate: 4 wave-independent nodes per block ----------------
__global__ __launch_bounds__(256) void k_gat_agg1e(
    const int* __restrict__ rp, const int* __restrict__ srcs, const unsigned* __restrict__ ed1,
    const bf16* __restrict__ hp,                 // [N,64]
    const float* __restrict__ als, const float* __restrict__ ald,
    const float* __restrict__ bias64, bf16* __restrict__ out){
  const int wid = threadIdx.x >> 6, l = threadIdx.x & 63;
  const int n = blockIdx.x*4 + wid;
  if(n >= N_NODES) return;
  int eg = l >> 3, c8 = l & 7;
  __shared__ float sw_s[4][64];
  __shared__ int   ssrc_s[4][64];
  float* sw = sw_s[wid];
  int* ssrc = ssrc_s[wid];
  int s0 = rp[n], e0 = rp[n+1];
  if((unsigned)s0 > N_EDGES){ s0=0; e0=0; }
  if(e0 < s0 || (unsigned)e0 > N_EDGES) e0 = s0;
  float aldn = ald[n];
  float wsum_l = 0.f, dsum_l = 0.f;
  float acc[8] = {0.f,0.f,0.f,0.f,0.f,0.f,0.f,0.f};
  const unsigned short* hpu = (const unsigned short*)hp;
  int base = s0;
  int pm = min(64, e0 - base);
  int r_sn = 0; unsigned r_ew = 0;
  if(base < e0 && l < pm){
    r_sn = __builtin_nontemporal_load(&srcs[base+l]);
    r_ew = __builtin_nontemporal_load(&ed1[base+l]);
  }
  while(base < e0){
    int m = pm;
    if(l < m){
      int sn = r_sn; if((unsigned)sn >= N_NODES) sn = 0;
      ssrc[l] = sn;
      float ed = us2f((unsigned short)(r_ew & 0xffff));
      float sc = als[sn] + aldn + ed;
      sc = sc > 0.f ? sc : NEG_SLOPE*sc;
      sc = fminf(sc, 30.f);
      float w = __expf(sc);
      sw[l] = w;
      wsum_l += w; dsum_l += ed;
    }
    wave_lds_fence();
    int nbase = base + 64;
    pm = min(64, e0 - nbase);
    if(nbase < e0 && l < pm){
      r_sn = __builtin_nontemporal_load(&srcs[nbase+l]);
      r_ew = __builtin_nontemporal_load(&ed1[nbase+l]);
    }
    #pragma unroll 8
    for(int i=0;i<m;i+=8){
      int j = i + eg;
      if(j < m){
        int row = ssrc[j];
        float w = sw[j];
        uint4 u = *(const uint4*)&hpu[(size_t)row*64 + 8*c8];
        acc8(acc, w, u);
      }
    }
    __builtin_amdgcn_wave_barrier();
    base = nbase;
  }
  #pragma unroll
  for(int o=1;o<64;o<<=1){ wsum_l += __shfl_xor(wsum_l, o); dsum_l += __shfl_xor(dsum_l, o); }
  #pragma unroll
  for(int q=0;q<8;q++){
    acc[q] += __shfl_xor(acc[q], 8);
    acc[q] += __shfl_xor(acc[q], 16);
    acc[q] += __shfl_xor(acc[q], 32);
  }
  if(l < 8){
    float deg = (float)(e0 - s0);
    float sdot = deg > 0.f ? dsum_l/deg : 0.f;
    float sc = als[n] + aldn + sdot;
    sc = sc > 0.f ? sc : NEG_SLOPE*sc;
    sc = fminf(sc, 30.f);
    float wself = __expf(sc);
    float self[8];
    unp8(self, *(const uint4*)&hpu[(size_t)n*64 + 8*l]);
    float4 b0 = *(const float4*)&bias64[8*l];
    float4 b1 = *(const float4*)&bias64[8*l + 4];
    float bi[8] = {b0.x,b0.y,b0.z,b0.w,b1.x,b1.y,b1.z,b1.w};
    float inv = 1.f/(wsum_l + wself);
    float o8[8];
    #pragma unroll
    for(int q=0;q<8;q++) o8[q] = (acc[q] + wself*self[q])*inv + bi[q];
    uint4 st;
    st.x = pk2(o8[0],o8[1]); st.y = pk2(o8[2],o8[3]);
    st.z = pk2(o8[4],o8[5]); st.w = pk2(o8[6],o8[7]);
    *(uint4*)&((unsigned short*)out)[(size_t)n*64 + 8*l] = st;
  }
}

// ---------------- GCN aggregate: 4 wave-independent nodes per block ----------------
__global__ __launch_bounds__(256) void k_gcn_agg(
    const int* __restrict__ rp, const int* __restrict__ srcs,
    const float* __restrict__ dinv, const bf16* __restrict__ gp,
    const float* __restrict__ bias, bf16* __restrict__ out){
  const int wid = threadIdx.x >> 6, l = threadIdx.x & 63;
  const int n = blockIdx.x*4 + wid;
  if(n >= N_NODES) return;
  int eg = l >> 3, c8 = l & 7;
  __shared__ float sw_s[4][64];
  __shared__ int   ssrc_s[4][64];
  float* sw = sw_s[wid];
  int* ssrc = ssrc_s[wid];
  int s0 = rp[n], e0 = rp[n+1];
  if((unsigned)s0 > N_EDGES){ s0=0; e0=0; }
  if(e0 < s0 || (unsigned)e0 > N_EDGES) e0 = s0;
  float dn = dinv[n];
  float acc[8] = {0.f,0.f,0.f,0.f,0.f,0.f,0.f,0.f};
  const unsigned short* gpu = (const unsigned short*)gp;
  int base = s0;
  int pm = min(64, e0 - base);
  int r_sn = 0;
  if(base < e0 && l < pm){
    r_sn = __builtin_nontemporal_load(&srcs[base+l]);
  }
  while(base < e0){
    int m = pm;
    if(l < m){
      int sn = r_sn; if((unsigned)sn >= N_NODES) sn = 0;
      ssrc[l]=sn; sw[l]=dinv[sn];
    }
    wave_lds_fence();
    int nbase = base + 64;
    pm = min(64, e0 - nbase);
    if(nbase < e0 && l < pm){
      r_sn = __builtin_nontemporal_load(&srcs[nbase+l]);
    }
    #pragma unroll 8
    for(int i=0;i<m;i+=8){
      int j = i + eg;
      if(j < m){
        int row = ssrc[j];
        float w = sw[j];
        uint4 u = *(const uint4*)&gpu[(size_t)row*64 + 8*c8];
        acc8(acc, w, u);
      }
    }
    __builtin_amdgcn_wave_barrier();
    base = nbase;
  }
  #pragma unroll
  for(int q=0;q<8;q++){
    acc[q] += __shfl_xor(acc[q], 8);
    acc[q] += __shfl_xor(acc[q], 16);
    acc[q] += __shfl_xor(acc[q], 32);
  }
  if(l < 8){
    float self[8];
    unp8(self, *(const uint4*)&gpu[(size_t)n*64 + 8*l]);
    float4 b0 = *(const float4*)&bias[8*l];
    float4 b1 = *(const float4*)&bias[8*l + 4];
    float bi[8] = {b0.x,b0.y,b0.z,b0.w,b1.x,b1.y,b1.z,b1.w};
    float o8[8];
    #pragma unroll
    for(int q=0;q<8;q++) o8[q] = dn*(acc[q] + dn*self[q]) + bi[q];
    uint4 st;
    st.x = pk2(o8[0],o8[1]); st.y = pk2(o8[2],o8[3]);
    st.z = pk2(o8[4],o8[5]); st.w = pk2(o8[6],o8[7]);
    *(uint4*)&((unsigned short*)out)[(size_t)n*64 + 8*l] = st;
  }
}

// ---------------- BN stats (bf16 input) ----------------
template<int C>
__global__ void k_colstats(const bf16* __restrict__ X, float* __restrict__ sums){
  constexpr int RPB = 128;
  constexpr int RSTEP = 256 / C;
  int c = threadIdx.x % C;
  int r0 = threadIdx.x / C;
  int rbeg = blockIdx.x * RPB;
  int rend = min(N_NODES, rbeg + RPB);
  const unsigned short* Xu = (const unsigned short*)X;
  float s = 0.f, q = 0.f;
  for(int r = rbeg + r0; r < rend; r += RSTEP){
    float v = sane(us2f(Xu[(size_t)r*C + c]));
    s += v; q += v*v;
  }
  atomicAdd(&sums[c], s);
  atomicAdd(&sums[C + c], q);
}

// ---------------- mean pool with fused BN+ReLU (bf16 input), 64-row blocks ----------------
__global__ __launch_bounds__(64) void k_pool3(
    const bf16* __restrict__ h, const int* __restrict__ batch,
    const float* __restrict__ sums, const float* __restrict__ g4,
    const float* __restrict__ b4,
    float* __restrict__ psum, float* __restrict__ pcnt){
  int t = threadIdx.x;
  int n0 = blockIdx.x * 64;
  int n1 = min(N_NODES, n0 + 64);
  if(n0 >= n1) return;
  const float invN = 1.0f / (float)N_NODES;
  float mean = sums[t]*invN;
  float var = fmaxf(sums[64+t]*invN - mean*mean, 0.f);
  float rstd = rsqrtf(var + BN_EPS);
  float gg = g4[t], bb = b4[t];
  const unsigned short* hu = (const unsigned short*)h;
  int cur = batch[n0]; if((unsigned)cur >= N_GRAPHS) cur = 0;
  float acc = 0.f; int cl = 0;
  for(int n = n0; n < n1; n++){
    int g = batch[n]; if((unsigned)g >= N_GRAPHS) g = 0;
    if(g != cur){
      atomicAdd(&psum[cur*64 + t], acc);
      if(t == 0) atomicAdd(&pcnt[cur], (float)cl);
      acc = 0.f; cl = 0; cur = g;
    }
    float y = (sane(us2f(hu[(size_t)n*64 + t]))-mean)*rstd*gg + bb;
    acc += fmaxf(y, 0.f);
    cl++;
  }
  atomicAdd(&psum[cur*64 + t], acc);
  if(t == 0) atomicAdd(&pcnt[cur], (float)cl);
}

// ---------------- head MLPs + output ----------------
__device__ __forceinline__ void stO(void* o, size_t i, float v, int m){
  if(m) ((float*)o)[i] = v; else ((bf16*)o)[i] = f2b(v);
}

__global__ __launch_bounds__(128) void k_head(
    const float* __restrict__ psum, const float* __restrict__ pcnt,
    const float* __restrict__ exf,
    const float* __restrict__ Wex1, const float* __restrict__ bex1,
    const float* __restrict__ Wex2, const float* __restrict__ bex2,
    const float* __restrict__ Wc1, const float* __restrict__ bc1,
    const float* __restrict__ Wc2, const float* __restrict__ bc2,
    const void* __restrict__ xdet, void* __restrict__ dout){
  int m0 = detect_mode_block(xdet);
  int g = blockIdx.x; int t = threadIdx.x;
  __shared__ float ci[128];
  __shared__ float e1[64];
  __shared__ float comb[128];
  __shared__ float red[128];
  if(t < 64){
    float c = fmaxf(pcnt[g], 1.f);
    float xp = sane(psum[g*64 + t]) / c;
    ci[t] = xp;
    stO(dout, 256 + (size_t)g*64 + t, xp, m0);
  } else {
    int j = t - 64;
    float s = bex1[j];
    for(int k=0;k<32;k++) s += exf[g*32 + k] * Wex1[k*64 + j];
    e1[j] = fmaxf(s, 0.f);
  }
  __syncthreads();
  if(t >= 64){
    int j = t - 64;
    float s = bex2[j];
    for(int k=0;k<64;k++) s += e1[k] * Wex2[k*64 + j];
    ci[64 + j] = fmaxf(s, 0.f);
  }
  __syncthreads();
  {
    float s = bc1[t];
    for(int k=0;k<128;k++) s += ci[k] * Wc1[k*128 + t];
    s = fmaxf(s, 0.f);
    comb[t] = s;
    stO(dout, 256 + 16384 + (size_t)g*128 + t, s, m0);
  }
  __syncthreads();
  red[t] = comb[t] * Wc2[t];
  __syncthreads();
  for(int o=64;o>0;o>>=1){ if(t<o) red[t]+=red[t+o]; __syncthreads(); }
  if(t==0) stO(dout, g, red[0] + bc2[0], m0);
}

// ---------------- launch ----------------
extern "C" void kernel_launch(void* const* d_in, const int* in_sizes, int n_in,
                              void* d_out, int out_size, void* d_ws, size_t ws_size,
                              hipStream_t stream){
  const void* x    = d_in[0];
  const void* ea   = d_in[1];
  const int* ei    = (const int*)d_in[3];
  const int* batch = (const int*)d_in[4];
  const int* src = ei;
  const int* dst = ei + N_EDGES;

  char* base = (char*)d_ws;
  size_t off = 0;
  auto alloc = [&](size_t bytes) -> void* {
    void* r = base + off;
    off += (bytes + 255) & ~(size_t)255;
    return r;
  };
  int*   cnt    = (int*)  alloc((size_t)N_NODES*4);
  int*   fill   = (int*)  alloc((size_t)N_NODES*4);
  float* bnstat = (float*)alloc(4096);
  float* pool   = (float*)alloc((size_t)(N_GRAPHS*64 + N_GRAPHS)*4);
  size_t zbytes = off;
  int*   rp      = (int*)  alloc((size_t)(N_NODES+1)*4);
  int*   bsum    = (int*)  alloc(256*4);
  int*   srcs    = (int*)  alloc((size_t)N_EDGES*4);
  u32x2* ed4     = (u32x2*)alloc((size_t)N_EDGES*8);
  unsigned* ed1  = (unsigned*)alloc((size_t)N_EDGES*4);
  float* dinv    = (float*)alloc((size_t)N_NODES*4);
  float* w_e     = (float*)alloc(64*4);
  float* als4    = (float*)alloc((size_t)N_NODES*4*4);
  float* ald4    = (float*)alloc((size_t)N_NODES*4*4);
  float* wbank   = (float*)alloc(80000*4);
  bf16*  wt      = (bf16*) alloc((size_t)40960*2);         // transposed bf16 weights
  bf16*  hp      = (bf16*) alloc((size_t)N_NODES*256*2);
  bf16*  outb    = (bf16*) alloc((size_t)N_NODES*256*2);   // bf16 activations

  bf16* out1 = outb;
  bf16* out2 = outb;                             // aliases (previous dead)
  bf16* out3 = outb + (size_t)N_NODES*64;
  bf16* out4 = outb + (size_t)N_NODES*128;
  float* bn1 = bnstat;
  float* bn2 = bnstat + 512;
  float* bn3 = bnstat + 640;
  float* bn4 = bnstat + 768;
  float* psum = pool;
  float* pcnt = pool + N_GRAPHS*64;

  bf16* wt1  = wt;            // [256][64]
  bf16* wt2  = wt + 16384;    // [64][256]
  bf16* wtg1 = wt + 32768;    // [64][64]
  bf16* wtg2 = wt + 36864;    // [64][64]

  const int segidx[NSEG] = {2, 5,6,7,8,9,10,11,12, 13,14,15,16,17,18,19,20,
                            21,22,23,24, 25,26,27,28, 29,30,31,32, 33,34,35,36};
  const int segn[NSEG] = {8192, 16384,256,256,2048,256,256,256,256,
                          16384,64,64,512,64,64,64,64,
                          4096,64,64,64, 4096,64,64,64,
                          2048,64,4096,64, 16384,128,128,1};
  Bank bk;
  int offs[NSEG]; int acc0 = 0;
  for(int i=0;i<NSEG;i++){ bk.p[i]=d_in[segidx[i]]; bk.n[i]=segn[i]; bk.off[i]=acc0; offs[i]=acc0; acc0+=segn[i]; }
  const float* f_exf = wbank + offs[0];
  const float* fas1 = wbank+offs[2]; const float* fad1 = wbank+offs[3];
  const float* fb1  = wbank+offs[6];
  const float* fg1 = wbank+offs[7]; const float* fbe1 = wbank+offs[8];
  const float* fas2 = wbank+offs[10]; const float* fad2 = wbank+offs[11];
  const float* fb2 = wbank+offs[14];
  const float* fg2 = wbank+offs[15]; const float* fbe2 = wbank+offs[16];
  const float* fbg1 = wbank+offs[18]; const float* fg3 = wbank+offs[19];
  const float* fbe3= wbank+offs[20];
  const float* fbg2 = wbank+offs[22]; const float* fg4 = wbank+offs[23];
  const float* fbe4= wbank+offs[24];
  const float* fWex1=wbank+offs[25]; const float* fbex1= wbank+offs[26];
  const float* fWex2=wbank+offs[27]; const float* fbex2= wbank+offs[28];
  const float* fWc1= wbank+offs[29]; const float* fbc1 = wbank+offs[30];
  const float* fWc2= wbank+offs[31]; const float* fbc2 = wbank+offs[32];

  const int nbN  = (N_NODES + 255)/256;
  const int nbE  = (N_EDGES + 255)/256;
  const int nbT  = (N_NODES + 63)/64;
  const int nbA  = (N_NODES + 3)/4;      // 4 wave-independent nodes per block
  const int nbP  = (N_NODES + 63)/64;    // pool blocks (64 rows each)

  hipMemsetAsync(d_ws, 0, zbytes, stream);
  // mega prep: count | convert | wt(raw) | we(raw)
  k_prep<<<PREP_COUNT + PREP_CONV + PREP_WT + 1, 256, 0, stream>>>(
      bk, x, dst, cnt, wbank, wt,
      d_in[5], d_in[13], d_in[21], d_in[25],
      d_in[8], d_in[9], d_in[16], d_in[17], w_e);
  k_blocksum<<<nbN,256,0,stream>>>(cnt, bsum);
  k_scan_write<<<nbN,256,0,stream>>>(cnt, bsum, rp, dinv, nbN);
  k_fill<<<nbE,256,0,stream>>>(src, dst, rp, fill, ea, x, w_e, srcs, ed4, ed1);

  // GAT layer 1 (MFMA on raw x + fused alpha dots -> aggregate)
  k_gemmA_mfma<<<nbT,256,0,stream>>>(x, wt1, hp, N_NODES, fas1, fad1, als4, ald4);
  k_gat_agg4<<<nbA,256,0,stream>>>(rp, srcs, ed4, hp, als4, ald4, fb1, out1);
  k_colstats<256><<<(N_NODES+127)/128,256,0,stream>>>(out1, bn1);

  // GAT layer 2 (1 head) — BN1+ReLU + alpha dots fused into MFMA
  k_gemmB_mfma<256><<<nbT,256,0,stream>>>(out1, wt2, hp, N_NODES, bn1, fg1, fbe1,
                                          fas2, fad2, als4, ald4);
  k_gat_agg1e<<<nbA,256,0,stream>>>(rp, srcs, ed1, hp, als4, ald4, fb2, out2);
  k_colstats<64><<<(N_NODES+127)/128,256,0,stream>>>(out2, bn2);

  // GCN layer 1 — BN2+ReLU fused
  k_gemmB_mfma<64><<<nbT,256,0,stream>>>(out2, wtg1, hp, N_NODES, bn2, fg2, fbe2,
                                         nullptr, nullptr, nullptr, nullptr);
  k_gcn_agg<<<nbA,256,0,stream>>>(rp, srcs, dinv, hp, fbg1, out3);
  k_colstats<64><<<(N_NODES+127)/128,256,0,stream>>>(out3, bn3);

  // GCN layer 2 — BN3+ReLU fused
  k_gemmB_mfma<64><<<nbT,256,0,stream>>>(out3, wtg2, hp, N_NODES, bn3, fg3, fbe3,
                                         nullptr, nullptr, nullptr, nullptr);
  k_gcn_agg<<<nbA,256,0,stream>>>(rp, srcs, dinv, hp, fbg2, out4);
  k_colstats<64><<<(N_NODES+127)/128,256,0,stream>>>(out4, bn4);

  // pool (BN4+ReLU fused) + head
  k_pool3<<<nbP,64,0,stream>>>(out4, batch, bn4, fg4, fbe4, psum, pcnt);
  k_head<<<N_GRAPHS,128,0,stream>>>(psum, pcnt, f_exf, fWex1, fbex1, fWex2, fbex2,
                                    fWc1, fbc1, fWc2, fbc2, x, (void*)d_out);
}